// Round 4
// baseline (829.373 us; speedup 1.0000x reference)
//
#include <hip/hip_runtime.h>
#include <math.h>

// Problem constants
constexpr int B = 32, T = 2048, P = 128, K = 256, R = 8, M = 64;
constexpr int BT = B * T;                 // 65536 rows
constexpr int TAU = 5;
constexpr int NSEG = (T + TAU - 1) / TAU; // 410 segments
constexpr float INV_TAU_X = 1.0f / 100.0f;
constexpr float INV_TAU_Z = 1.0f / 100.0f;

typedef short bf16x4 __attribute__((ext_vector_type(4)));
typedef short bf16x8 __attribute__((ext_vector_type(8)));
typedef float f32x4 __attribute__((ext_vector_type(4)));

// fp32 <-> bf16 (RNE)
static __device__ __forceinline__ short f2bf(float f) {
  unsigned u = __builtin_bit_cast(unsigned, f);
  u += 0x7FFF + ((u >> 16) & 1);
  return (short)(u >> 16);
}
static __device__ __forceinline__ float bf2f(short h) {
  unsigned u = ((unsigned)(unsigned short)h) << 16;
  return __builtin_bit_cast(float, u);
}

// async global->LDS, 16 B per lane; LDS dest = wave-uniform base + lane*16.
static __device__ __forceinline__ void async16(const void* g, void* l) {
  __builtin_amdgcn_global_load_lds(
      (const __attribute__((address_space(1))) void*)g,
      (__attribute__((address_space(3))) void*)l, 16, 0, 0);
}

// ---------------------------------------------------------------------------
// Split in_seq (fp32) into bf16 hi/lo arrays once.
// ---------------------------------------------------------------------------
__global__ __launch_bounds__(256) void split_kernel(
    const float* __restrict__ in, short* __restrict__ h,
    short* __restrict__ l, int n4) {
  const int i = blockIdx.x * 256 + threadIdx.x;
  if (i >= n4) return;
  const float4 v = ((const float4*)in)[i];
  const float f[4] = {v.x, v.y, v.z, v.w};
  bf16x4 ph, pl;
#pragma unroll
  for (int q = 0; q < 4; ++q) {
    ph[q] = f2bf(f[q]);
    pl[q] = f2bf(f[q] - bf2f(ph[q]));
  }
  ((bf16x4*)h)[i] = ph;
  ((bf16x4*)l)[i] = pl;
}

// ---------------------------------------------------------------------------
// C = tanh(A @ W^T + bias), split-bf16 MFMA (hh + lh + hl, fp32 acc).
// A arrives PRE-SPLIT (Ah/Al bf16) -> staged via global_load_lds width 16
// (no VALU, no pad; m97 structure). W is fp32, split during staging (small).
// Block tile 128 x BN, BK=64, 4 waves (warpM=wave&1 64 rows, warpN=wave>>1).
// SPLIT_OUT: epilogue writes bf16 hi/lo (feeds next GEMM); else fp32 out.
// ---------------------------------------------------------------------------
template <int KIN, int KOUT, int BN, bool SPLIT_OUT>
__global__ __launch_bounds__(256) void gemm_mfma(
    const short* __restrict__ Ah, const short* __restrict__ Al,
    const float* __restrict__ W, const float* __restrict__ bias,
    short* __restrict__ Ch, short* __restrict__ Cl,
    float* __restrict__ Cf) {
  constexpr int BK = 64;
  constexpr int WNT = BN / 32;  // 16-col sub-tiles per wave
  static_assert(KIN % BK == 0, "K tiling");

  __shared__ short AsH[128 * BK];
  __shared__ short AsL[128 * BK];
  __shared__ short BsH[BN * BK];
  __shared__ short BsL[BN * BK];

  const int tid = threadIdx.x;
  const int wave = tid >> 6, lane = tid & 63;
  const int l16 = lane & 15, quad = lane >> 4;
  const int warpM = wave & 1, warpN = wave >> 1;
  const int row0 = blockIdx.x * 128;
  const int col0 = blockIdx.y * BN;

  f32x4 acc[4][WNT];
#pragma unroll
  for (int i = 0; i < 4; ++i)
#pragma unroll
    for (int j = 0; j < WNT; ++j) acc[i][j] = (f32x4){0.f, 0.f, 0.f, 0.f};

  for (int k0 = 0; k0 < KIN; k0 += BK) {
    // A: 16 async 1-KB issues per buffer; issue t covers rows 8t..8t+7.
#pragma unroll
    for (int t = wave; t < 16; t += 4) {
      const int r = t * 8 + (lane >> 3);
      const size_t goff = (size_t)(row0 + r) * KIN + k0 + (lane & 7) * 8;
      async16(&Ah[goff], &AsH[t * 512]);
      async16(&Al[goff], &AsL[t * 512]);
    }
    // B: fp32 weights, split in-flight (BN*64 elems).
#pragma unroll
    for (int c = tid; c < BN * 8; c += 256) {
      const int r = c >> 3, kc = (c & 7) * 8;
      const float* src = &W[(size_t)(col0 + r) * KIN + k0 + kc];
      const float4 v0 = *(const float4*)src;
      const float4 v1 = *(const float4*)(src + 4);
      const float f[8] = {v0.x, v0.y, v0.z, v0.w, v1.x, v1.y, v1.z, v1.w};
      bf16x8 ph, pl;
#pragma unroll
      for (int q = 0; q < 8; ++q) {
        ph[q] = f2bf(f[q]);
        pl[q] = f2bf(f[q] - bf2f(ph[q]));
      }
      *(bf16x8*)&BsH[r * BK + kc] = ph;
      *(bf16x8*)&BsL[r * BK + kc] = pl;
    }
    __syncthreads();  // drains vmcnt (async A) + lgkm (B stores)

#pragma unroll
    for (int kk = 0; kk < BK; kk += 32) {
      const int ko = kk + quad * 8;
      bf16x8 ah[4], al[4], bh[WNT], bl[WNT];
#pragma unroll
      for (int i = 0; i < 4; ++i) {
        const int off = (warpM * 64 + i * 16 + l16) * BK + ko;
        ah[i] = *(const bf16x8*)&AsH[off];
        al[i] = *(const bf16x8*)&AsL[off];
      }
#pragma unroll
      for (int j = 0; j < WNT; ++j) {
        const int off = (warpN * WNT * 16 + j * 16 + l16) * BK + ko;
        bh[j] = *(const bf16x8*)&BsH[off];
        bl[j] = *(const bf16x8*)&BsL[off];
      }
#pragma unroll
      for (int i = 0; i < 4; ++i)
#pragma unroll
        for (int j = 0; j < WNT; ++j) {
          acc[i][j] = __builtin_amdgcn_mfma_f32_16x16x32_bf16(ah[i], bh[j],
                                                              acc[i][j], 0, 0, 0);
          acc[i][j] = __builtin_amdgcn_mfma_f32_16x16x32_bf16(al[i], bh[j],
                                                              acc[i][j], 0, 0, 0);
          acc[i][j] = __builtin_amdgcn_mfma_f32_16x16x32_bf16(ah[i], bl[j],
                                                              acc[i][j], 0, 0, 0);
        }
    }
    __syncthreads();
  }

  // Epilogue. C/D map: col = lane&15, row = quad*4 + reg.
#pragma unroll
  for (int j = 0; j < WNT; ++j) {
    const int col = col0 + warpN * WNT * 16 + j * 16 + l16;
    const float bj = bias[col];
#pragma unroll
    for (int i = 0; i < 4; ++i) {
      const int rbase = row0 + warpM * 64 + i * 16 + quad * 4;
#pragma unroll
      for (int r = 0; r < 4; ++r) {
        const float v = tanhf(acc[i][j][r] + bj);
        const size_t idx = (size_t)(rbase + r) * KOUT + col;
        if (SPLIT_OUT) {
          const short h = f2bf(v);
          Ch[idx] = h;
          Cl[idx] = f2bf(v - bf2f(h));
        } else {
          Cf[idx] = v;
        }
      }
    }
  }
}

// ---------------------------------------------------------------------------
// Scan: reset every TAU=5 makes segments independent; one wave per chain.
// 512 threads (8 chains/block) -> 32 waves/CU at 36.5 KB LDS. NO inner
// barriers: tz_s rows are wave-private (intra-wave ds_write->ds_read order
// is guaranteed by lgkmcnt). Reads split x_seq, writes split x_states.
// ---------------------------------------------------------------------------
__global__ __launch_bounds__(512) void scan_kernel(
    const short* __restrict__ xh, const short* __restrict__ xl,  // x_seq split
    const float* __restrict__ z_seq,                             // fp32
    const float* __restrict__ Lm, const float* __restrict__ Rm,
    const float* __restrict__ Wz, const float* __restrict__ Az_w,
    const float* __restrict__ Az_b,
    short* __restrict__ xsh, short* __restrict__ xsl,  // x_states split
    float* __restrict__ z_pred) {
  __shared__ float Wz_s[M][M + 1];  // stride 65 -> 2-way max on matvec reads
  __shared__ float Az_s[R][M];
  __shared__ float Azb_s[R];
  __shared__ float Lt_s[R][K];
  __shared__ float Rt_s[R][K];
  __shared__ float tz_s[8][M];  // per-wave rows

  const int tid = threadIdx.x;
  for (int i = tid; i < M * M; i += 512) Wz_s[i >> 6][i & 63] = Wz[i];
  for (int i = tid; i < R * M; i += 512) Az_s[i >> 6][i & 63] = Az_w[i];
  if (tid < R) Azb_s[tid] = Az_b[tid];
  for (int i = tid; i < K * R; i += 512) {
    const int k = i / R, r = i % R;
    Lt_s[r][k] = Lm[i];
    Rt_s[r][k] = Rm[i];
  }
  __syncthreads();

  const int wave = tid >> 6;
  const int lane = tid & 63;
  const int chain = blockIdx.x * 8 + wave;
  const int b = chain / NSEG;
  const int seg = chain % NSEG;
  const int t0 = seg * TAU;

  float x[4], z;
  {
    const size_t base = ((size_t)b * T + t0);
#pragma unroll
    for (int j = 0; j < 4; ++j)
      x[j] = bf2f(xh[base * K + lane + 64 * j]) + bf2f(xl[base * K + lane + 64 * j]);
    z = z_seq[base * M + lane];
  }

  for (int tt = 0; tt < TAU; ++tt) {
    const int t = t0 + tt;
    // z update: z += (tanh(z) @ Wz^T - z)/100
    const float tz = tanhf(z);
    tz_s[wave][lane] = tz;  // wave-private row, no barrier needed
    float zacc = 0.f;
#pragma unroll 8
    for (int j = 0; j < M; ++j) zacc += tz_s[wave][j] * Wz_s[lane][j];
    const float znew = z + (zacc - z) * INV_TAU_Z;

    // s = sigmoid(z_new @ Az_w^T + b)
    float s[R];
#pragma unroll
    for (int r = 0; r < R; ++r) {
      float p = znew * Az_s[r][lane];
#pragma unroll
      for (int off = 32; off > 0; off >>= 1) p += __shfl_xor(p, off, 64);
      s[r] = 1.f / (1.f + expf(-(p + Azb_s[r])));
    }

    // x update
    float tx4[4];
#pragma unroll
    for (int j = 0; j < 4; ++j) tx4[j] = tanhf(x[j]);
    float v[R];
#pragma unroll
    for (int r = 0; r < R; ++r) {
      float p = 0.f;
#pragma unroll
      for (int j = 0; j < 4; ++j) p += tx4[j] * Lt_s[r][lane + 64 * j];
#pragma unroll
      for (int off = 32; off > 0; off >>= 1) p += __shfl_xor(p, off, 64);
      v[r] = p * s[r];
    }
#pragma unroll
    for (int j = 0; j < 4; ++j) {
      float xacc = 0.f;
#pragma unroll
      for (int r = 0; r < R; ++r) xacc += v[r] * Rt_s[r][lane + 64 * j];
      x[j] = x[j] + (xacc - x[j]) * INV_TAU_X;
    }

    if (t < T) {
      const size_t o = ((size_t)b * T + t);
#pragma unroll
      for (int j = 0; j < 4; ++j) {
        const short h = f2bf(x[j]);
        xsh[o * K + lane + 64 * j] = h;
        xsl[o * K + lane + 64 * j] = f2bf(x[j] - bf2f(h));
      }
      z_pred[o * M + lane] = znew;
    }
    z = znew;
  }
}

// ---------------------------------------------------------------------------
// Buffers: ws = 4 x (BT*K bf16) = S0h,S0l,S1h,S1l (134 MB, same as r3).
// Z enc slots (4 x BT*M bf16 = 33.5 MB) carved inside S1h (dead window).
// in_seq split lives in the x_pred output region until the last GEMM.
// Schedule: split_in; ex1..ex3 (S0<->S1, x_seq ends in S0); de1r/de2r ->
// x_recon; ez1..ez3 -> z_seq (fp32, d_out); scan (S0 -> S1 states, z_pred);
// de1p/de2p -> x_pred.
// ---------------------------------------------------------------------------
extern "C" void kernel_launch(void* const* d_in, const int* in_sizes, int n_in,
                              void* d_out, int out_size, void* d_ws,
                              size_t ws_size, hipStream_t stream) {
  const float* in_seq = (const float*)d_in[0];
  const float* Lm    = (const float*)d_in[1];
  const float* Rm    = (const float*)d_in[2];
  const float* Wz    = (const float*)d_in[3];
  const float* Az_w  = (const float*)d_in[4];
  const float* Az_b  = (const float*)d_in[5];
  const float* ex1_w = (const float*)d_in[6];
  const float* ex1_b = (const float*)d_in[7];
  const float* ex2_w = (const float*)d_in[8];
  const float* ex2_b = (const float*)d_in[9];
  const float* ex3_w = (const float*)d_in[10];
  const float* ex3_b = (const float*)d_in[11];
  const float* ez1_w = (const float*)d_in[12];
  const float* ez1_b = (const float*)d_in[13];
  const float* ez2_w = (const float*)d_in[14];
  const float* ez2_b = (const float*)d_in[15];
  const float* ez3_w = (const float*)d_in[16];
  const float* ez3_b = (const float*)d_in[17];
  const float* de1_w = (const float*)d_in[18];
  const float* de1_b = (const float*)d_in[19];
  const float* de2_w = (const float*)d_in[20];
  const float* de2_b = (const float*)d_in[21];

  float* out = (float*)d_out;
  float* x_pred  = out;                                        // BT*P
  float* x_recon = out + (size_t)BT * P;                       // BT*P
  float* z_pred  = out + (size_t)2 * BT * P;                   // BT*M
  float* z_seq   = out + (size_t)2 * BT * P + (size_t)BT * M;  // BT*M

  short* S0h = (short*)d_ws;
  short* S0l = S0h + (size_t)BT * K;
  short* S1h = S0l + (size_t)BT * K;
  short* S1l = S1h + (size_t)BT * K;
  // z-encoder slots inside S1h's span (dead between de2r and scan)
  short* Z0h = S1h;
  short* Z0l = S1h + (size_t)BT * M;
  short* Z1h = S1h + (size_t)2 * BT * M;
  short* Z1l = S1h + (size_t)3 * BT * M;
  // in_seq split in x_pred region (dead until the final GEMM)
  short* INh = (short*)x_pred;
  short* INl = INh + (size_t)BT * P;

  const dim3 blk(256);
  const dim3 gx(BT / 128, 2);    // KOUT=256
  const dim3 g128(BT / 128, 1);  // KOUT=128
  const dim3 g64(BT / 128, 1);   // KOUT=64

  split_kernel<<<dim3((BT * P / 4 + 255) / 256), blk, 0, stream>>>(
      in_seq, INh, INl, BT * P / 4);

  // x encoder
  gemm_mfma<128, 256, 128, true><<<gx, blk, 0, stream>>>(INh, INl, ex1_w, ex1_b, S0h, S0l, nullptr);
  gemm_mfma<256, 256, 128, true><<<gx, blk, 0, stream>>>(S0h, S0l, ex2_w, ex2_b, S1h, S1l, nullptr);
  gemm_mfma<256, 256, 128, true><<<gx, blk, 0, stream>>>(S1h, S1l, ex3_w, ex3_b, S0h, S0l, nullptr);
  // x_recon decoder
  gemm_mfma<256, 256, 128, true><<<gx, blk, 0, stream>>>(S0h, S0l, de1_w, de1_b, S1h, S1l, nullptr);
  gemm_mfma<256, 128, 128, false><<<g128, blk, 0, stream>>>(S1h, S1l, de2_w, de2_b, nullptr, nullptr, x_recon);
  // z encoder
  gemm_mfma<128, 64, 64, true><<<g64, blk, 0, stream>>>(INh, INl, ez1_w, ez1_b, Z0h, Z0l, nullptr);
  gemm_mfma<64, 64, 64, true><<<g64, blk, 0, stream>>>(Z0h, Z0l, ez2_w, ez2_b, Z1h, Z1l, nullptr);
  gemm_mfma<64, 64, 64, false><<<g64, blk, 0, stream>>>(Z1h, Z1l, ez3_w, ez3_b, nullptr, nullptr, z_seq);
  // scan
  scan_kernel<<<dim3(B * NSEG / 8), dim3(512), 0, stream>>>(
      S0h, S0l, z_seq, Lm, Rm, Wz, Az_w, Az_b, S1h, S1l, z_pred);
  // x_pred decoder
  gemm_mfma<256, 256, 128, true><<<gx, blk, 0, stream>>>(S1h, S1l, de1_w, de1_b, S0h, S0l, nullptr);
  gemm_mfma<256, 128, 128, false><<<g128, blk, 0, stream>>>(S0h, S0l, de2_w, de2_b, nullptr, nullptr, x_pred);
}

// Round 5
// 581.234 us; speedup vs baseline: 1.4269x; 1.4269x over previous
//
#include <hip/hip_runtime.h>
#include <math.h>

// Problem constants
constexpr int B = 32, T = 2048, P = 128, K = 256, R = 8, M = 64;
constexpr int BT = B * T;                 // 65536 rows
constexpr int TAU = 5;
constexpr int NSEG = (T + TAU - 1) / TAU; // 410 segments
constexpr float INV_TAU_X = 1.0f / 100.0f;
constexpr float INV_TAU_Z = 1.0f / 100.0f;

typedef short bf16x4 __attribute__((ext_vector_type(4)));
typedef short bf16x8 __attribute__((ext_vector_type(8)));
typedef float f32x4 __attribute__((ext_vector_type(4)));

// fp32 <-> bf16 (RNE)
static __device__ __forceinline__ short f2bf(float f) {
  unsigned u = __builtin_bit_cast(unsigned, f);
  u += 0x7FFF + ((u >> 16) & 1);
  return (short)(u >> 16);
}
static __device__ __forceinline__ float bf2f(short h) {
  unsigned u = ((unsigned)(unsigned short)h) << 16;
  return __builtin_bit_cast(float, u);
}

// fast transcendentals (v_exp + v_rcp, ~1e-6 rel — invisible vs 2e-2 thresh)
static __device__ __forceinline__ float tanh_fast(float x) {
  const float e = __expf(2.f * x);
  return 1.f - 2.f * __builtin_amdgcn_rcpf(e + 1.f);
}
static __device__ __forceinline__ float sigmoid_fast(float x) {
  return __builtin_amdgcn_rcpf(1.f + __expf(-x));
}

// async global->LDS, 16 B/lane; LDS dest = wave-uniform base + lane*16.
static __device__ __forceinline__ void async16(const void* g, void* l) {
  __builtin_amdgcn_global_load_lds(
      (const __attribute__((address_space(1))) void*)g,
      (__attribute__((address_space(3))) void*)l, 16, 0, 0);
}

// ---------------------------------------------------------------------------
// Generic fp32 -> split bf16 (hi/lo) elementwise kernel.
// ---------------------------------------------------------------------------
__global__ __launch_bounds__(256) void split_kernel(
    const float* __restrict__ in, short* __restrict__ h,
    short* __restrict__ l, int n4) {
  const int i = blockIdx.x * 256 + threadIdx.x;
  if (i >= n4) return;
  const float4 v = ((const float4*)in)[i];
  const float f[4] = {v.x, v.y, v.z, v.w};
  bf16x4 ph, pl;
#pragma unroll
  for (int q = 0; q < 4; ++q) {
    ph[q] = f2bf(f[q]);
    pl[q] = f2bf(f[q] - bf2f(ph[q]));
  }
  ((bf16x4*)h)[i] = ph;
  ((bf16x4*)l)[i] = pl;
}

// Batched split of the 8 weight matrices into one region: weight w's hi at
// dst+hoff[w], lo at dst+hoff[w]+4*n4[w].
struct W8 {
  const float* src[8];
  unsigned hoff[8];  // in shorts
  unsigned n4[8];
};
__global__ __launch_bounds__(256) void split8_kernel(W8 p, short* __restrict__ dst) {
  const int w = blockIdx.y;
  const int i = blockIdx.x * 256 + threadIdx.x;
  if (i >= (int)p.n4[w]) return;
  const float4 v = ((const float4*)p.src[w])[i];
  const float f[4] = {v.x, v.y, v.z, v.w};
  bf16x4 ph, pl;
#pragma unroll
  for (int q = 0; q < 4; ++q) {
    ph[q] = f2bf(f[q]);
    pl[q] = f2bf(f[q] - bf2f(ph[q]));
  }
  *(bf16x4*)&dst[p.hoff[w] + i * 4] = ph;
  *(bf16x4*)&dst[p.hoff[w] + p.n4[w] * 4 + i * 4] = pl;
}

// ---------------------------------------------------------------------------
// C = tanh(A @ W^T + bias), split-bf16 MFMA (hh + lh + hl, fp32 acc).
// A AND B pre-split bf16 -> 100% async16 staging, zero staging VALU.
// XOR-swizzled LDS image: lane fetches global chunk (l&7)^(l>>3) so stored
// slot = row*8 + (chunk ^ (row&7)); frag reads use chunk ^ (l16&7) ->
// exactly 8 dwords/bank per ds_read_b128 (balanced; fixes r4's 8x conflict).
// Block tile 128 x BN, BK=64, 4 waves (warpM=wave&1, warpN=wave>>1).
// ---------------------------------------------------------------------------
template <int KIN, int KOUT, int BN, bool SPLIT_OUT>
__global__ __launch_bounds__(256) void gemm_mfma(
    const short* __restrict__ Ah, const short* __restrict__ Al,
    const short* __restrict__ Bh, const short* __restrict__ Bl,
    const float* __restrict__ bias,
    short* __restrict__ Ch, short* __restrict__ Cl,
    float* __restrict__ Cf) {
  constexpr int BK = 64;        // shorts per row tile (= 8 chunks of 16 B)
  constexpr int WNT = BN / 32;  // 16-col sub-tiles per wave
  constexpr int NB = BN / 8;    // B async issues per buffer
  static_assert(KIN % BK == 0, "K tiling");

  __shared__ short AsH[128 * BK];
  __shared__ short AsL[128 * BK];
  __shared__ short BsH[BN * BK];
  __shared__ short BsL[BN * BK];

  const int tid = threadIdx.x;
  const int wave = tid >> 6, lane = tid & 63;
  const int l16 = lane & 15, quad = lane >> 4;
  const int sw = l16 & 7;  // read-side swizzle key
  const int warpM = wave & 1, warpN = wave >> 1;
  const int row0 = blockIdx.x * 128;
  const int col0 = blockIdx.y * BN;
  // staging-side: lane covers row (8t + l>>3), fetches swizzled chunk:
  const int srow = lane >> 3;
  const int schunk = (lane & 7) ^ srow;

  f32x4 acc[4][WNT];
#pragma unroll
  for (int i = 0; i < 4; ++i)
#pragma unroll
    for (int j = 0; j < WNT; ++j) acc[i][j] = (f32x4){0.f, 0.f, 0.f, 0.f};

  for (int k0 = 0; k0 < KIN; k0 += BK) {
    // A: 16 issues x 1 KB per buffer (rows 8t..8t+7).
#pragma unroll
    for (int t = wave; t < 16; t += 4) {
      const size_t goff = (size_t)(row0 + t * 8 + srow) * KIN + k0 + schunk * 8;
      async16(&Ah[goff], &AsH[t * 512]);
      async16(&Al[goff], &AsL[t * 512]);
    }
    // B: NB issues per buffer.
#pragma unroll
    for (int t = wave; t < NB; t += 4) {
      const size_t goff = (size_t)(col0 + t * 8 + srow) * KIN + k0 + schunk * 8;
      async16(&Bh[goff], &BsH[t * 512]);
      async16(&Bl[goff], &BsL[t * 512]);
    }
    __syncthreads();  // drains vmcnt for all async issues

#pragma unroll
    for (int kk = 0; kk < 2; ++kk) {  // two 32-k halves of BK
      const int qc = kk * 4 + quad;   // chunk index 0..7
      const int qs = (qc ^ sw) * 8;   // swizzled short offset within row
      bf16x8 ah[4], al[4], bh[WNT], bl[WNT];
#pragma unroll
      for (int i = 0; i < 4; ++i) {
        const int off = (warpM * 64 + i * 16 + l16) * BK + qs;
        ah[i] = *(const bf16x8*)&AsH[off];
        al[i] = *(const bf16x8*)&AsL[off];
      }
#pragma unroll
      for (int j = 0; j < WNT; ++j) {
        const int off = (warpN * WNT * 16 + j * 16 + l16) * BK + qs;
        bh[j] = *(const bf16x8*)&BsH[off];
        bl[j] = *(const bf16x8*)&BsL[off];
      }
#pragma unroll
      for (int i = 0; i < 4; ++i)
#pragma unroll
        for (int j = 0; j < WNT; ++j) {
          acc[i][j] = __builtin_amdgcn_mfma_f32_16x16x32_bf16(ah[i], bh[j],
                                                              acc[i][j], 0, 0, 0);
          acc[i][j] = __builtin_amdgcn_mfma_f32_16x16x32_bf16(al[i], bh[j],
                                                              acc[i][j], 0, 0, 0);
          acc[i][j] = __builtin_amdgcn_mfma_f32_16x16x32_bf16(ah[i], bl[j],
                                                              acc[i][j], 0, 0, 0);
        }
    }
    __syncthreads();
  }

  // Epilogue. C/D map: col = lane&15, row = quad*4 + reg.
#pragma unroll
  for (int j = 0; j < WNT; ++j) {
    const int col = col0 + warpN * WNT * 16 + j * 16 + l16;
    const float bj = bias[col];
#pragma unroll
    for (int i = 0; i < 4; ++i) {
      const int rbase = row0 + warpM * 64 + i * 16 + quad * 4;
#pragma unroll
      for (int r = 0; r < 4; ++r) {
        const float v = tanh_fast(acc[i][j][r] + bj);
        const size_t idx = (size_t)(rbase + r) * KOUT + col;
        if (SPLIT_OUT) {
          const short h = f2bf(v);
          Ch[idx] = h;
          Cl[idx] = f2bf(v - bf2f(h));
        } else {
          Cf[idx] = v;
        }
      }
    }
  }
}

// ---------------------------------------------------------------------------
// Scan: reset every TAU=5 -> independent (batch, segment) chains; one wave
// per chain, 8 waves/block, NO inner barriers (tz_s rows wave-private).
// Writes x_states IN-PLACE over x_seq (each wave reads only its seed row
// 5*seg before writing rows 5seg..5seg+4; rows disjoint across waves).
// Wz staged stride-68 for conflict-balanced b128 row reads (16/step vs 64);
// tz broadcast read as float4; Az cached in registers; fast tanh/sigmoid.
// ---------------------------------------------------------------------------
__global__ __launch_bounds__(512) void scan_kernel(
    const short* xh, const short* xl,          // x_seq split (aliased w/ out!)
    const float* __restrict__ z_seq,           // fp32
    const float* __restrict__ Lm, const float* __restrict__ Rm,
    const float* __restrict__ Wz, const float* __restrict__ Az_w,
    const float* __restrict__ Az_b,
    short* xsh, short* xsl,                    // x_states split (== xh/xl)
    float* __restrict__ z_pred) {
  __shared__ float Wz_s[M][68];  // stride 68: 16B-aligned rows, balanced banks
  __shared__ float Lt_s[R][K];   // transposed: Lt[r][k]
  __shared__ float Rt_s[R][K];
  __shared__ float tz_s[8][M];   // per-wave rows (256 B aligned)

  const int tid = threadIdx.x;
  for (int i = tid; i < M * M; i += 512) Wz_s[i >> 6][i & 63] = Wz[i];
  for (int i = tid; i < K * R; i += 512) {
    const int k = i / R, r = i % R;
    Lt_s[r][k] = Lm[i];
    Rt_s[r][k] = Rm[i];
  }
  __syncthreads();

  const int wave = tid >> 6;
  const int lane = tid & 63;
  const int chain = blockIdx.x * 8 + wave;
  const int b = chain / NSEG;
  const int seg = chain % NSEG;
  const int t0 = seg * TAU;

  // per-lane register caches (reused all 5 steps)
  float azw[R], azb[R];
#pragma unroll
  for (int r = 0; r < R; ++r) {
    azw[r] = Az_w[r * M + lane];
    azb[r] = Az_b[r];
  }

  float x[4], z;
  {
    const size_t base = ((size_t)b * T + t0);
#pragma unroll
    for (int j = 0; j < 4; ++j)
      x[j] = bf2f(xh[base * K + lane + 64 * j]) + bf2f(xl[base * K + lane + 64 * j]);
    z = z_seq[base * M + lane];
  }

  const float4* wrow = (const float4*)&Wz_s[lane][0];  // lane*272 B, 16-al.
  const float4* trow = (const float4*)&tz_s[wave][0];

  for (int tt = 0; tt < TAU; ++tt) {
    const int t = t0 + tt;
    // z update: z += (tanh(z) @ Wz^T - z)/100
    const float tz = tanh_fast(z);
    tz_s[wave][lane] = tz;  // wave-private row; intra-wave DS order suffices
    float zacc = 0.f;
#pragma unroll
    for (int j = 0; j < 16; ++j) {
      const float4 w = wrow[j], tv = trow[j];
      zacc += w.x * tv.x + w.y * tv.y + w.z * tv.z + w.w * tv.w;
    }
    const float znew = z + (zacc - z) * INV_TAU_Z;

    // s = sigmoid(z_new @ Az^T + b)
    float s[R];
#pragma unroll
    for (int r = 0; r < R; ++r) {
      float p = znew * azw[r];
#pragma unroll
      for (int off = 32; off > 0; off >>= 1) p += __shfl_xor(p, off, 64);
      s[r] = sigmoid_fast(p + azb[r]);
    }

    // x update: u = tanh(x) @ L ; v = u*s ; x += (v @ Rm^T - x)/100
    float tx4[4];
#pragma unroll
    for (int j = 0; j < 4; ++j) tx4[j] = tanh_fast(x[j]);
    float v[R];
#pragma unroll
    for (int r = 0; r < R; ++r) {
      float p = 0.f;
#pragma unroll
      for (int j = 0; j < 4; ++j) p += tx4[j] * Lt_s[r][lane + 64 * j];
#pragma unroll
      for (int off = 32; off > 0; off >>= 1) p += __shfl_xor(p, off, 64);
      v[r] = p * s[r];
    }
#pragma unroll
    for (int j = 0; j < 4; ++j) {
      float xacc = 0.f;
#pragma unroll
      for (int r = 0; r < R; ++r) xacc += v[r] * Rt_s[r][lane + 64 * j];
      x[j] = x[j] + (xacc - x[j]) * INV_TAU_X;
    }

    if (t < T) {
      const size_t o = ((size_t)b * T + t);
#pragma unroll
      for (int j = 0; j < 4; ++j) {
        const short h = f2bf(x[j]);
        xsh[o * K + lane + 64 * j] = h;
        xsl[o * K + lane + 64 * j] = f2bf(x[j] - bf2f(h));
      }
      z_pred[o * M + lane] = znew;
    }
    z = znew;
  }
}

// ---------------------------------------------------------------------------
// Buffers/schedule (scan in-place on S0 frees S1's live range for weights):
//  ws:  S0h,S0l,S1h,S1l (4 x BT*K shorts = 128 MiB exactly).
//  out: x_pred | x_recon | z_pred | z_seq.
//  IN  (split in_seq)           -> x_pred region      (live 1..8)
//  Wall (8 split weights 1.1MB) -> z_pred region      (live 2..10, scan@12 kills)
//  Z0/Z1 (z activations)        -> S1h                (live 8..10)
//  Wde1 (split de1_w)           -> IN region base     (live 11..13)
//  Wde2 (split de2_w)           -> S0 base            (live 14..15)
//  1 split_in; 2 split8; 3 ex1 IN->S0; 4 ex2 S0->S1; 5 ex3 S1->S0(x_seq);
//  6 de1r S0->S1; 7 de2r S1->x_recon; 8 ez1 IN->Z0; 9 ez2 Z0->Z1;
//  10 ez3 Z1->z_seq; 11 split de1_w->IN; 12 scan S0 in-place + z_pred;
//  13 de1p S0->S1 (B=Wde1); 14 split de2_w->S0; 15 de2p S1->x_pred (B=Wde2)
// ---------------------------------------------------------------------------
extern "C" void kernel_launch(void* const* d_in, const int* in_sizes, int n_in,
                              void* d_out, int out_size, void* d_ws,
                              size_t ws_size, hipStream_t stream) {
  const float* in_seq = (const float*)d_in[0];
  const float* Lm    = (const float*)d_in[1];
  const float* Rm    = (const float*)d_in[2];
  const float* Wz    = (const float*)d_in[3];
  const float* Az_w  = (const float*)d_in[4];
  const float* Az_b  = (const float*)d_in[5];
  const float* ex1_w = (const float*)d_in[6];
  const float* ex1_b = (const float*)d_in[7];
  const float* ex2_w = (const float*)d_in[8];
  const float* ex2_b = (const float*)d_in[9];
  const float* ex3_w = (const float*)d_in[10];
  const float* ex3_b = (const float*)d_in[11];
  const float* ez1_w = (const float*)d_in[12];
  const float* ez1_b = (const float*)d_in[13];
  const float* ez2_w = (const float*)d_in[14];
  const float* ez2_b = (const float*)d_in[15];
  const float* ez3_w = (const float*)d_in[16];
  const float* ez3_b = (const float*)d_in[17];
  const float* de1_w = (const float*)d_in[18];
  const float* de1_b = (const float*)d_in[19];
  const float* de2_w = (const float*)d_in[20];
  const float* de2_b = (const float*)d_in[21];

  float* out = (float*)d_out;
  float* x_pred  = out;                                        // BT*P
  float* x_recon = out + (size_t)BT * P;                       // BT*P
  float* z_pred  = out + (size_t)2 * BT * P;                   // BT*M
  float* z_seq   = out + (size_t)2 * BT * P + (size_t)BT * M;  // BT*M

  short* S0h = (short*)d_ws;
  short* S0l = S0h + (size_t)BT * K;
  short* S1h = S0l + (size_t)BT * K;
  short* S1l = S1h + (size_t)BT * K;
  short* Z0h = S1h;                       // z slots inside S1h (dead window)
  short* Z0l = S1h + (size_t)BT * M;
  short* Z1h = S1h + (size_t)2 * BT * M;
  short* Z1l = S1h + (size_t)3 * BT * M;
  short* INh = (short*)x_pred;            // split in_seq in x_pred region
  short* INl = INh + (size_t)BT * P;
  short* Wr  = (short*)z_pred;            // split-weight block in z_pred region
  short* WD1 = (short*)x_pred;            // de1 re-split (after IN dies)
  short* WD2 = (short*)d_ws;              // de2 re-split (after S0 dies)

  // weight offsets in Wr (shorts): hi at hoff, lo at hoff + 4*n4
  const unsigned HO_EX1 = 0,      HO_EX2 = 65536,  HO_EX3 = 196608;
  const unsigned HO_DE1 = 327680, HO_DE2 = 458752;
  const unsigned HO_EZ1 = 524288, HO_EZ2 = 540672, HO_EZ3 = 548864;

  const dim3 blk(256);
  const dim3 gx(BT / 128, 2);    // KOUT=256
  const dim3 g128(BT / 128, 1);  // KOUT=128
  const dim3 g64(BT / 128, 1);   // KOUT=64

  // 1: split in_seq
  split_kernel<<<dim3(BT * P / 4 / 256), blk, 0, stream>>>(in_seq, INh, INl, BT * P / 4);
  // 2: split all 8 weights into Wr
  W8 w8;
  w8.src[0] = ex1_w; w8.hoff[0] = HO_EX1; w8.n4[0] = 8192;
  w8.src[1] = ex2_w; w8.hoff[1] = HO_EX2; w8.n4[1] = 16384;
  w8.src[2] = ex3_w; w8.hoff[2] = HO_EX3; w8.n4[2] = 16384;
  w8.src[3] = de1_w; w8.hoff[3] = HO_DE1; w8.n4[3] = 16384;
  w8.src[4] = de2_w; w8.hoff[4] = HO_DE2; w8.n4[4] = 8192;
  w8.src[5] = ez1_w; w8.hoff[5] = HO_EZ1; w8.n4[5] = 2048;
  w8.src[6] = ez2_w; w8.hoff[6] = HO_EZ2; w8.n4[6] = 1024;
  w8.src[7] = ez3_w; w8.hoff[7] = HO_EZ3; w8.n4[7] = 1024;
  split8_kernel<<<dim3(64, 8), blk, 0, stream>>>(w8, Wr);

  // 3-5: x encoder 128->256->256->256
  gemm_mfma<128, 256, 128, true><<<gx, blk, 0, stream>>>(
      INh, INl, Wr + HO_EX1, Wr + HO_EX1 + 32768, ex1_b, S0h, S0l, nullptr);
  gemm_mfma<256, 256, 128, true><<<gx, blk, 0, stream>>>(
      S0h, S0l, Wr + HO_EX2, Wr + HO_EX2 + 65536, ex2_b, S1h, S1l, nullptr);
  gemm_mfma<256, 256, 128, true><<<gx, blk, 0, stream>>>(
      S1h, S1l, Wr + HO_EX3, Wr + HO_EX3 + 65536, ex3_b, S0h, S0l, nullptr);
  // 6-7: x_recon decoder
  gemm_mfma<256, 256, 128, true><<<gx, blk, 0, stream>>>(
      S0h, S0l, Wr + HO_DE1, Wr + HO_DE1 + 65536, de1_b, S1h, S1l, nullptr);
  gemm_mfma<256, 128, 128, false><<<g128, blk, 0, stream>>>(
      S1h, S1l, Wr + HO_DE2, Wr + HO_DE2 + 32768, de2_b, nullptr, nullptr, x_recon);
  // 8-10: z encoder 128->64->64->64
  gemm_mfma<128, 64, 64, true><<<g64, blk, 0, stream>>>(
      INh, INl, Wr + HO_EZ1, Wr + HO_EZ1 + 8192, ez1_b, Z0h, Z0l, nullptr);
  gemm_mfma<64, 64, 64, true><<<g64, blk, 0, stream>>>(
      Z0h, Z0l, Wr + HO_EZ2, Wr + HO_EZ2 + 4096, ez2_b, Z1h, Z1l, nullptr);
  gemm_mfma<64, 64, 64, false><<<g64, blk, 0, stream>>>(
      Z1h, Z1l, Wr + HO_EZ3, Wr + HO_EZ3 + 4096, ez3_b, nullptr, nullptr, z_seq);
  // 11: re-split de1_w into dead IN region (for de1p)
  split_kernel<<<dim3(64), blk, 0, stream>>>(de1_w, WD1, WD1 + 65536, 16384);
  // 12: scan (in-place on S0), z_pred out
  scan_kernel<<<dim3(B * NSEG / 8), dim3(512), 0, stream>>>(
      S0h, S0l, z_seq, Lm, Rm, Wz, Az_w, Az_b, S0h, S0l, z_pred);
  // 13: de1p S0 -> S1
  gemm_mfma<256, 256, 128, true><<<gx, blk, 0, stream>>>(
      S0h, S0l, WD1, WD1 + 65536, de1_b, S1h, S1l, nullptr);
  // 14: re-split de2_w into dead S0 head (for de2p)
  split_kernel<<<dim3(32), blk, 0, stream>>>(de2_w, WD2, WD2 + 32768, 8192);
  // 15: de2p S1 -> x_pred
  gemm_mfma<256, 128, 128, false><<<g128, blk, 0, stream>>>(
      S1h, S1l, WD2, WD2 + 32768, de2_b, nullptr, nullptr, x_pred);
}